// Round 3
// baseline (100.699 us; speedup 1.0000x reference)
//
#include <hip/hip_runtime.h>
#include <stdint.h>
#include <math.h>

constexpr int NB = 8;
constexpr int NC = 32;
constexpr int NK = 512;
constexpr int ROWS = 4;          // rows (i) per block

// ---------------------------------------------------------------------------
// Threefry2x32 (Random123 / JAX), key = (0, 42), x0 = 0 (flat idx < 2^32)
// partitionable mode: bits(n) = o0 ^ o1
// ---------------------------------------------------------------------------
__device__ __forceinline__ uint32_t rotl32(uint32_t x, uint32_t r) {
    return (x << r) | (x >> (32u - r));
}

__device__ __forceinline__ uint32_t jax_random_bits(uint32_t n) {
    const uint32_t k0 = 0u, k1 = 42u;
    const uint32_t ks2 = k0 ^ k1 ^ 0x1BD11BDAu;
    uint32_t x0 = 0u + k0, x1 = n + k1;

    x0 += x1; x1 = rotl32(x1, 13); x1 ^= x0;
    x0 += x1; x1 = rotl32(x1, 15); x1 ^= x0;
    x0 += x1; x1 = rotl32(x1, 26); x1 ^= x0;
    x0 += x1; x1 = rotl32(x1,  6); x1 ^= x0;
    x0 += k1; x1 += ks2 + 1u;

    x0 += x1; x1 = rotl32(x1, 17); x1 ^= x0;
    x0 += x1; x1 = rotl32(x1, 29); x1 ^= x0;
    x0 += x1; x1 = rotl32(x1, 16); x1 ^= x0;
    x0 += x1; x1 = rotl32(x1, 24); x1 ^= x0;
    x0 += ks2; x1 += k0 + 2u;

    x0 += x1; x1 = rotl32(x1, 13); x1 ^= x0;
    x0 += x1; x1 = rotl32(x1, 15); x1 ^= x0;
    x0 += x1; x1 = rotl32(x1, 26); x1 ^= x0;
    x0 += x1; x1 = rotl32(x1,  6); x1 ^= x0;
    x0 += k0; x1 += k1 + 3u;

    x0 += x1; x1 = rotl32(x1, 17); x1 ^= x0;
    x0 += x1; x1 = rotl32(x1, 29); x1 ^= x0;
    x0 += x1; x1 = rotl32(x1, 16); x1 ^= x0;
    x0 += x1; x1 = rotl32(x1, 24); x1 ^= x0;
    x0 += k1; x1 += ks2 + 4u;

    x0 += x1; x1 = rotl32(x1, 13); x1 ^= x0;
    x0 += x1; x1 = rotl32(x1, 15); x1 ^= x0;
    x0 += x1; x1 = rotl32(x1, 26); x1 ^= x0;
    x0 += x1; x1 = rotl32(x1,  6); x1 ^= x0;
    x0 += ks2; x1 += k0 + 5u;

    return x0 ^ x1;
}

// u (f64, JAX-exact) and fast f32 L = -log(u).
__device__ __forceinline__ float fastL(uint32_t bits, double& ud) {
    const double S = 1.0 - 1e-10, T = 1e-10;
    uint32_t fb = (bits >> 9) | 0x3F800000u;
    float bf = __uint_as_float(fb) - 1.0f;            // exact 23-bit uniform [0,1)
    ud = (double)bf * S + T;                          // >= 1e-10 by construction
    if (bf <= 0.5f) {
        return -logf((float)ud);
    } else {
        double vm1 = S * ((double)bf - 1.0);          // u-1 in f64 (no cancel loss)
        return -log1pf((float)vm1);
    }
}

// rare exact-path fallback (~2e-4 of non-skipped elements)
__device__ __noinline__ bool decide_slow(double a2, double c2,
                                         double u0, double u1) {
    return a2 * (-log(u1)) >= c2 * (-log(u0));
}

// Decision: sample==1 iff logit+g0 >= -logit+g1  <=>  a2*L1 >= c2*L0
// a2 = (0.99*Dm)^2, c2 = (D - 0.99*Dm)^2  (diag: a2=99^2, c2=1)
// Deterministic-false: L0 >= 1.192e-7, L1 <= 23.026 => if c2 > 1.95e8*a2
// the inequality can never hold (log-space margin ~0.0096 >> f64 noise).
__device__ __forceinline__ bool decide(double D, double q /*0.99*Dm*/,
                                       bool diag, uint32_t n0) {
    double a2, c2;
    if (diag) { a2 = 9801.0; c2 = 1.0; }
    else {
        a2 = q * q;
        double t = D - q;
        c2 = t * t;
        if (c2 > 1.95e8 * a2) return false;           // no RNG needed
    }
    uint32_t bits0 = jax_random_bits(n0);
    uint32_t bits1 = jax_random_bits(n0 + 1u);
    double u0d, u1d;
    float L0f = fastL(bits0, u0d);
    float L1f = fastL(bits1, u1d);

    float lhs = (float)a2 * L1f;
    float rhs = (float)c2 * L0f;
    float diff = lhs - rhs;
    if (fabsf(diff) > 1e-4f * (lhs + rhs))
        return diff >= 0.0f;                          // fast path, sign-safe
    return decide_slow(a2, c2, u0d, u1d);
}

// ---------------------------------------------------------------------------
__global__ void zero_out_kernel(float4* __restrict__ out) {
    out[blockIdx.x * blockDim.x + threadIdx.x] = make_float4(0.f, 0.f, 0.f, 0.f);
}

// grid (NK/ROWS, NB) x 256 threads; thread owns cols j = 2*tid, 2*tid+1
__global__ __launch_bounds__(256) void sample_kernel(
    const float* __restrict__ amp, const float* __restrict__ ph,
    const float* __restrict__ A, const float* __restrict__ wav,
    const float* __restrict__ wpv, float* __restrict__ out)
{
    const int i0  = blockIdx.x * ROWS;
    const int b   = blockIdx.y;
    const int tid = threadIdx.x;
    const int j0  = 2 * tid;

    __shared__ double sred[ROWS][4];
    __shared__ double s_q[ROWS];

    const double wa = (double)wav[0];
    const double wp = (double)wpv[0];

    const float* __restrict__ ab = amp + (size_t)b * NC * NK;
    const float* __restrict__ pb = ph  + (size_t)b * NC * NK;

    double acc[2][ROWS];
    #pragma unroll
    for (int it = 0; it < 2; ++it)
        #pragma unroll
        for (int r = 0; r < ROWS; ++r) acc[it][r] = 0.0;

    // dist accumulation: same per-(i,j) fma chain over c as round-2 (matches)
    #pragma unroll 4
    for (int c = 0; c < NC; ++c) {
        // uniform (blockIdx-only) addresses -> scalar loads into SGPRs
        double fi_r[ROWS];
        #pragma unroll
        for (int r = 0; r < ROWS; ++r) {
            float ai = ab[c * NK + i0 + r];
            float pi = pb[c * NK + i0 + r];
            fi_r[r] = wa * (double)ai + wp * (double)pi;
        }
        // vector side: 8B coalesced loads
        float2 av = *(const float2*)(ab + c * NK + j0);
        float2 pv = *(const float2*)(pb + c * NK + j0);
        double fj0 = wa * (double)av.x + wp * (double)pv.x;
        double fj1 = wa * (double)av.y + wp * (double)pv.y;
        #pragma unroll
        for (int r = 0; r < ROWS; ++r) {
            double d0 = fi_r[r] - fj0; acc[0][r] = fma(d0, d0, acc[0][r]);
            double d1 = fi_r[r] - fj1; acc[1][r] = fma(d1, d1, acc[1][r]);
        }
    }

    double D[2][ROWS];
    #pragma unroll
    for (int it = 0; it < 2; ++it) {
        int j = j0 + it;
        double ad = (double)A[j * NK + j];
        double a2 = ad * ad;
        #pragma unroll
        for (int r = 0; r < ROWS; ++r)
            D[it][r] = acc[it][r] * a2 + 1e-10;       // same rounding as R2
    }

    // per-row min over j != i (exact, order-independent)
    #pragma unroll
    for (int r = 0; r < ROWS; ++r) {
        const int i = i0 + r;
        double m = 1e300;
        #pragma unroll
        for (int it = 0; it < 2; ++it) {
            int j = j0 + it;
            if (j != i) m = fmin(m, D[it][r]);
        }
        #pragma unroll
        for (int off = 32; off > 0; off >>= 1)
            m = fmin(m, __shfl_down(m, off));
        if ((tid & 63) == 0) sred[r][tid >> 6] = m;
    }
    __syncthreads();
    if (tid < ROWS) {
        double m = fmin(fmin(sred[tid][0], sred[tid][1]),
                        fmin(sred[tid][2], sred[tid][3]));
        s_q[tid] = 0.99 * m;
    }
    __syncthreads();

    #pragma unroll
    for (int it = 0; it < 2; ++it) {
        const int j = j0 + it;
        #pragma unroll
        for (int r = 0; r < ROWS; ++r) {
            const int i = i0 + r;
            uint32_t n0 = 2u * (((uint32_t)(b * NK + i)) * NK + (uint32_t)j);
            if (decide(D[it][r], s_q[r], j == i, n0))
                atomicAdd(&out[i * NK + j], 0.125f);  // mean over B=8, exact
        }
    }
}

extern "C" void kernel_launch(void* const* d_in, const int* in_sizes, int n_in,
                              void* d_out, int out_size, void* d_ws, size_t ws_size,
                              hipStream_t stream) {
    const float* amp = (const float*)d_in[0];   // (8,32,512)
    const float* ph  = (const float*)d_in[1];   // (8,32,512)
    const float* A   = (const float*)d_in[2];   // (512,512)
    const float* wa  = (const float*)d_in[3];   // scalar
    const float* wp  = (const float*)d_in[4];   // scalar
    float* out = (float*)d_out;                 // (512,512) f32

    // d_out is poisoned 0xAA before every launch -> zero it (1 MB)
    zero_out_kernel<<<256, 256, 0, stream>>>((float4*)out);

    dim3 grid(NK / ROWS, NB);
    sample_kernel<<<grid, 256, 0, stream>>>(amp, ph, A, wa, wp, out);
}

// Round 5
// 84.921 us; speedup vs baseline: 1.1858x; 1.1858x over previous
//
#include <hip/hip_runtime.h>
#include <stdint.h>
#include <math.h>

constexpr int NB = 8;
constexpr int NC = 32;
constexpr int NK = 512;
constexpr int ROWS = 2;          // rows (i) per block

// ---------------------------------------------------------------------------
// Threefry2x32 (Random123 / JAX), key = (0, 42), x0 = 0 (flat idx < 2^32)
// partitionable mode: bits(n) = o0 ^ o1
// ---------------------------------------------------------------------------
__device__ __forceinline__ uint32_t rotl32(uint32_t x, uint32_t r) {
    return (x << r) | (x >> (32u - r));
}

__device__ __forceinline__ uint32_t jax_random_bits(uint32_t n) {
    const uint32_t k0 = 0u, k1 = 42u;
    const uint32_t ks2 = k0 ^ k1 ^ 0x1BD11BDAu;
    uint32_t x0 = 0u + k0, x1 = n + k1;

    x0 += x1; x1 = rotl32(x1, 13); x1 ^= x0;
    x0 += x1; x1 = rotl32(x1, 15); x1 ^= x0;
    x0 += x1; x1 = rotl32(x1, 26); x1 ^= x0;
    x0 += x1; x1 = rotl32(x1,  6); x1 ^= x0;
    x0 += k1; x1 += ks2 + 1u;

    x0 += x1; x1 = rotl32(x1, 17); x1 ^= x0;
    x0 += x1; x1 = rotl32(x1, 29); x1 ^= x0;
    x0 += x1; x1 = rotl32(x1, 16); x1 ^= x0;
    x0 += x1; x1 = rotl32(x1, 24); x1 ^= x0;
    x0 += ks2; x1 += k0 + 2u;

    x0 += x1; x1 = rotl32(x1, 13); x1 ^= x0;
    x0 += x1; x1 = rotl32(x1, 15); x1 ^= x0;
    x0 += x1; x1 = rotl32(x1, 26); x1 ^= x0;
    x0 += x1; x1 = rotl32(x1,  6); x1 ^= x0;
    x0 += k0; x1 += k1 + 3u;

    x0 += x1; x1 = rotl32(x1, 17); x1 ^= x0;
    x0 += x1; x1 = rotl32(x1, 29); x1 ^= x0;
    x0 += x1; x1 = rotl32(x1, 16); x1 ^= x0;
    x0 += x1; x1 = rotl32(x1, 24); x1 ^= x0;
    x0 += k1; x1 += ks2 + 4u;

    x0 += x1; x1 = rotl32(x1, 13); x1 ^= x0;
    x0 += x1; x1 = rotl32(x1, 15); x1 ^= x0;
    x0 += x1; x1 = rotl32(x1, 26); x1 ^= x0;
    x0 += x1; x1 = rotl32(x1,  6); x1 ^= x0;
    x0 += ks2; x1 += k0 + 5u;

    return x0 ^ x1;
}

// u (f64, JAX-exact) and fast f32 L = -log(u).
__device__ __forceinline__ float fastL(uint32_t bits, double& ud) {
    const double S = 1.0 - 1e-10, T = 1e-10;
    uint32_t fb = (bits >> 9) | 0x3F800000u;
    float bf = __uint_as_float(fb) - 1.0f;            // exact 23-bit uniform [0,1)
    ud = (double)bf * S + T;                          // >= 1e-10 by construction
    if (bf <= 0.5f) {
        return -logf((float)ud);
    } else {
        double vm1 = S * ((double)bf - 1.0);          // u-1 in f64 (no cancel loss)
        return -log1pf((float)vm1);
    }
}

// rare exact-path fallback
__device__ __noinline__ bool decide_slow(double a2, double c2,
                                         double u0, double u1) {
    return a2 * (-log(u1)) >= c2 * (-log(u0));
}

// RNG decision (element already survived the deterministic-false filter):
// sample==1 iff a2*L1 >= c2*L0;  a2=(0.99*Dm)^2, c2=(D-0.99*Dm)^2 (diag 9801/1)
__device__ __forceinline__ bool decide_rng(double D, double q /*0.99*Dm*/,
                                           bool diag, uint32_t n0) {
    double a2, c2;
    if (diag) { a2 = 9801.0; c2 = 1.0; }
    else      { a2 = q * q; double t = D - q; c2 = t * t; }

    uint32_t bits0 = jax_random_bits(n0);
    uint32_t bits1 = jax_random_bits(n0 + 1u);
    double u0d, u1d;
    float L0f = fastL(bits0, u0d);
    float L1f = fastL(bits1, u1d);

    float lhs = (float)a2 * L1f;
    float rhs = (float)c2 * L0f;
    float diff = lhs - rhs;
    if (fabsf(diff) > 1e-4f * (lhs + rhs))
        return diff >= 0.0f;                          // fast path, sign-safe
    return decide_slow(a2, c2, u0d, u1d);
}

// ---------------------------------------------------------------------------
// Prep (R2-proven): zero out (262144 f32 == grid), F = wa*amp+wp*ph (f64, ws),
// A2[j] = A_jj^2.  grid 1024 x 256.
// ---------------------------------------------------------------------------
__global__ void prep_kernel(const float* __restrict__ amp,
                            const float* __restrict__ ph,
                            const float* __restrict__ A,
                            const float* __restrict__ wav,
                            const float* __restrict__ wpv,
                            double* __restrict__ F,
                            double* __restrict__ A2,
                            float* __restrict__ out) {
    int t = blockIdx.x * 256 + threadIdx.x;
    out[t] = 0.0f;
    if (t < NB * NC * NK) {
        double wa = (double)wav[0], wp = (double)wpv[0];
        F[t] = wa * (double)amp[t] + wp * (double)ph[t];
    }
    if (t < NK) {
        double a = (double)A[t * NK + t];
        A2[t] = a * a;
    }
}

// ---------------------------------------------------------------------------
// Main: grid (NK/ROWS, NB) x 256. Thread owns cols j = 2*tid, 2*tid+1.
// Wave w owns j in [128w, 128w+128): compaction is WAVE-LOCAL (no cross-wave
// state, no LDS atomics; survivor D fetched via intra-wave shfl).
// ---------------------------------------------------------------------------
__global__ __launch_bounds__(256) void sample_kernel(
    const double* __restrict__ F, const double* __restrict__ A2,
    float* __restrict__ out)
{
    const int i0   = blockIdx.x * ROWS;
    const int b    = blockIdx.y;
    const int tid  = threadIdx.x;
    const int j0   = 2 * tid;
    const int lane = tid & 63;
    const int wv   = tid >> 6;          // wave index 0..3
    const int wjb  = wv * 128;          // wave's j base

    __shared__ unsigned char wlist[4][ROWS][128];   // wave-private lists, 1 KB
    __shared__ double sred[ROWS][4];
    __shared__ double s_q[ROWS];

    const double* __restrict__ Fb = F + (size_t)b * NC * NK;

    // ---- Phase 1: dist accumulation (same per-element fma chain as R1-R4)
    double acc[2][ROWS];
    #pragma unroll
    for (int it = 0; it < 2; ++it)
        #pragma unroll
        for (int r = 0; r < ROWS; ++r) acc[it][r] = 0.0;

    #pragma unroll 4
    for (int c = 0; c < NC; ++c) {
        double fr0 = Fb[c * NK + i0];         // uniform -> scalar loads
        double fr1 = Fb[c * NK + i0 + 1];
        double2 fj = *(const double2*)(Fb + c * NK + j0);   // 16B coalesced
        double d00 = fr0 - fj.x; acc[0][0] = fma(d00, d00, acc[0][0]);
        double d10 = fr0 - fj.y; acc[1][0] = fma(d10, d10, acc[1][0]);
        double d01 = fr1 - fj.x; acc[0][1] = fma(d01, d01, acc[0][1]);
        double d11 = fr1 - fj.y; acc[1][1] = fma(d11, d11, acc[1][1]);
    }

    double2 a2j = *(const double2*)(A2 + j0);
    double D[2][ROWS];
    #pragma unroll
    for (int r = 0; r < ROWS; ++r) {
        D[0][r] = acc[0][r] * a2j.x + 1e-10;   // same rounding as R1-R4
        D[1][r] = acc[1][r] * a2j.y + 1e-10;
    }

    // per-row min over j != i (exact, order-independent; R1-R3-proven path)
    #pragma unroll
    for (int r = 0; r < ROWS; ++r) {
        const int i = i0 + r;
        double m = 1e300;
        if (j0     != i) m = fmin(m, D[0][r]);
        if (j0 + 1 != i) m = fmin(m, D[1][r]);
        #pragma unroll
        for (int off = 32; off > 0; off >>= 1)
            m = fmin(m, __shfl_down(m, off));
        if (lane == 0) sred[r][wv] = m;
    }
    __syncthreads();
    if (tid < ROWS) {
        double m = fmin(fmin(sred[tid][0], sred[tid][1]),
                        fmin(sred[tid][2], sred[tid][3]));
        s_q[tid] = 0.99 * m;
    }
    __syncthreads();

    // ---- Phase 2: deterministic-false filter + WAVE-LOCAL compaction.
    // Skip (false for ANY draw) iff (D-q)^2 > 1.95e8*q^2:
    // r2 = a2/c2 < 5.128e-9 => max lhs = r2*23.026 = 1.181e-7 < L0min =
    // 1.1921e-7 (1% margin, exact f64). Diag always needs RNG.
    const unsigned long long ltmask = (1ull << lane) - 1ull;
    int nw[ROWS];
    #pragma unroll
    for (int r = 0; r < ROWS; ++r) {
        const int i = i0 + r;
        const double q = s_q[r];
        const double thr = 1.95e8 * (q * q);
        double t0 = D[0][r] - q;
        double t1 = D[1][r] - q;
        bool need0 = (j0     == i) || !(t0 * t0 > thr);
        bool need1 = (j0 + 1 == i) || !(t1 * t1 > thr);
        unsigned long long m0 = __ballot(need0);
        unsigned long long m1 = __ballot(need1);
        int c0 = __popcll(m0);
        nw[r] = c0 + __popcll(m1);
        // local element id jl = 2*lane + it  (j = wjb + jl), fits u8
        if (need0) wlist[wv][r][__popcll(m0 & ltmask)]      = (unsigned char)(2 * lane);
        if (need1) wlist[wv][r][c0 + __popcll(m1 & ltmask)] = (unsigned char)(2 * lane + 1);
    }
    // same-wave LDS RAW: ordered by program order + lgkmcnt, no barrier needed

    // ---- Phase 3: dense RNG decisions over the wave's own list
    #pragma unroll
    for (int r = 0; r < ROWS; ++r) {
        const int i = i0 + r;
        const double q = s_q[r];
        const int n = nw[r];                 // wave-uniform (from ballots)
        for (int k0v = 0; k0v < n; k0v += 64) {
            int k = k0v + lane;
            bool act = k < n;
            int jl = wlist[wv][r][act ? k : 0];   // in-bounds always
            int src = jl >> 1;
            // all-lane shfls (loop bound wave-uniform, no divergence here)
            double d0s = __shfl(D[0][r], src);
            double d1s = __shfl(D[1][r], src);
            double Dv = (jl & 1) ? d1s : d0s;
            int j = wjb + jl;
            uint32_t n0 = 2u * (((uint32_t)(b * NK + i)) * NK + (uint32_t)j);
            if (act && decide_rng(Dv, q, j == i, n0))
                atomicAdd(&out[i * NK + j], 0.125f);   // mean over B=8, exact
        }
    }
}

extern "C" void kernel_launch(void* const* d_in, const int* in_sizes, int n_in,
                              void* d_out, int out_size, void* d_ws, size_t ws_size,
                              hipStream_t stream) {
    const float* amp = (const float*)d_in[0];   // (8,32,512)
    const float* ph  = (const float*)d_in[1];   // (8,32,512)
    const float* A   = (const float*)d_in[2];   // (512,512)
    const float* wa  = (const float*)d_in[3];   // scalar
    const float* wp  = (const float*)d_in[4];   // scalar
    float* out = (float*)d_out;                 // (512,512) f32

    double* F  = (double*)d_ws;                    // 131072 f64 = 1 MB
    double* A2 = (double*)d_ws + NB * NC * NK;     // 512 f64

    prep_kernel<<<1024, 256, 0, stream>>>(amp, ph, A, wa, wp, F, A2, out);

    dim3 grid(NK / ROWS, NB);
    sample_kernel<<<grid, 256, 0, stream>>>(F, A2, out);
}